// Round 6
// baseline (740.045 us; speedup 1.0000x reference)
//
#include <hip/hip_runtime.h>
#include <hip/hip_bf16.h>

// SectorGCN R13: dual-sort pre-gather (R9 design), made budget-safe.
// Rounds 8/10/12 proved the scattered-LOAD wall: ~53 cy per distinct line per
// CU, invariant to MLP depth, cache residency, and cache-policy bits. R11
// ablation: the load alone is 276us; atomics+skeleton ~45us. Escape: row-sorted
// pass reads h SEQUENTIALLY and pre-scatters rows to he[pos] with fire-and-
// forget STORES (store path ~8x faster per line, per k_Ascatter evidence);
// both gather kernels then read fully coalesced. Workspace-adaptive: he buffer
// processed in {1,2,4,8} bucket-range phases to fit ws_size (pos overlaid in
// he region; hard capacity guards); falls back to the proven R12 path if even
// 8 phases don't fit. N=100000, E=3200000, d_in=128, d_h=16.

#define DH 16
#define BSH 6
#define BNODES 64
#define NB_MAX 1568
#define CHUNK 4096        // scatter chunk
#define HCHUNK 8192       // hist chunk
#define NSL 2             // pregather-path slices
#define NSL_FB 4          // fallback slices
#define SE_CAP 768        // fallback gather1 staged edges
#define SE2_CAP 1280      // fallback gather2 staged edges
#define HESLACK 65536     // he capacity slack (slots)

#define BFL(u) __uint_as_float((u) << 16)
#define BFH(u) __uint_as_float((u) & 0xFFFF0000u)

typedef unsigned int u32x2 __attribute__((ext_vector_type(2)));

static __device__ __forceinline__ uint2 ntload_u2(const uint2* p) {
    u32x2 v = __builtin_nontemporal_load((const u32x2*)p);
    return make_uint2(v.x, v.y);
}

// ---------- shared kernels ----------

// histogram of BOTH col-buckets and row-buckets in one pass (pregather path)
__global__ __launch_bounds__(256) void k_hist2(const int* __restrict__ row,
                                               const int* __restrict__ col,
                                               int* __restrict__ gCnt,
                                               int* __restrict__ rCnt, int E, int NB) {
    __shared__ int lc[NB_MAX];
    __shared__ int lr[NB_MAX];
    const int tid = threadIdx.x;
    for (int i = tid; i < NB; i += 256) { lc[i] = 0; lr[i] = 0; }
    __syncthreads();
    const int base = blockIdx.x * HCHUNK;
    #pragma unroll
    for (int k = 0; k < 32; ++k) {
        int e = base + tid + 256 * k;
        if (e < E) {
            atomicAdd(&lc[col[e] >> BSH], 1);
            atomicAdd(&lr[row[e] >> BSH], 1);
        }
    }
    __syncthreads();
    for (int i = tid; i < NB; i += 256) {
        if (lc[i]) atomicAdd(&gCnt[i], lc[i]);
        if (lr[i]) atomicAdd(&rCnt[i], lr[i]);
    }
}

// col-only histogram (fallback path)
__global__ __launch_bounds__(256) void k_Ahist(const int* __restrict__ col,
                                               int* __restrict__ gCnt, int E, int NB) {
    __shared__ int lh[NB_MAX];
    const int tid = threadIdx.x;
    for (int i = tid; i < NB; i += 256) lh[i] = 0;
    __syncthreads();
    const int base = blockIdx.x * HCHUNK;
    #pragma unroll
    for (int k = 0; k < 32; ++k) {
        int e = base + tid + 256 * k;
        if (e < E) atomicAdd(&lh[col[e] >> BSH], 1);
    }
    __syncthreads();
    for (int i = tid; i < NB; i += 256) {
        int v = lh[i];
        if (v) atomicAdd(&gCnt[i], v);
    }
}

// exclusive scan of cnt[NB], NB <= 2048 (2 elems/thread)
__global__ __launch_bounds__(1024) void k_Ascan(const int* __restrict__ cnt,
                                                int* __restrict__ basep,
                                                int* __restrict__ cursor,
                                                int NB, int E) {
    __shared__ int s[1024];
    const int t = threadIdx.x;
    const int i0 = 2 * t, i1 = 2 * t + 1;
    int a = (i0 < NB) ? cnt[i0] : 0;
    int b = (i1 < NB) ? cnt[i1] : 0;
    int v = a + b;
    s[t] = v;
    __syncthreads();
    for (int off = 1; off < 1024; off <<= 1) {
        int u = (t >= off) ? s[t - off] : 0;
        __syncthreads();
        s[t] += u;
        __syncthreads();
    }
    int ex = s[t] - v;
    if (i0 < NB) { basep[i0] = ex;     cursor[i0] = ex; }
    if (i1 < NB) { basep[i1] = ex + a; cursor[i1] = ex + a; }
    if (t == 0) basep[NB] = E;
}

// col-sort scatter; optionally records pos[e] = destination slot of edge e
__global__ __launch_bounds__(256) void k_Ascatter(const int* __restrict__ row,
                                                  const int* __restrict__ col,
                                                  const float* __restrict__ ew,
                                                  int* __restrict__ gCursor,
                                                  uint2* __restrict__ edata,
                                                  int* __restrict__ pos,
                                                  int E, int NB) {
    __shared__ int lh[NB_MAX];      // counts, then (globalRun - localBase)
    __shared__ int lbase[NB_MAX];
    __shared__ int lcur[NB_MAX];
    __shared__ int tsum[256];
    __shared__ unsigned short sbuck[CHUNK];
    __shared__ uint2 stage[CHUNK];  // 32 KB
    const int tid = threadIdx.x;
    for (int i = tid; i < NB; i += 256) lh[i] = 0;
    __syncthreads();
    const int base = blockIdx.x * CHUNK;
    int r_[16], c_[16];
    float w_[16];
    #pragma unroll
    for (int k = 0; k < 16; ++k) {
        int e = base + tid + 256 * k;
        bool ok = e < E;
        c_[k] = ok ? col[e] : -1;
        r_[k] = ok ? row[e] : 0;
        w_[k] = ok ? ew[e] : 0.f;
        if (ok) atomicAdd(&lh[c_[k] >> BSH], 1);
    }
    __syncthreads();
    const int t0 = tid * 8;
    int c8[8];
    int mysum = 0;
    #pragma unroll
    for (int k = 0; k < 8; ++k) {
        c8[k] = (t0 + k < NB) ? lh[t0 + k] : 0;
        mysum += c8[k];
    }
    tsum[tid] = mysum;
    __syncthreads();
    for (int off = 1; off < 256; off <<= 1) {
        int u = (tid >= off) ? tsum[tid - off] : 0;
        __syncthreads();
        tsum[tid] += u;
        __syncthreads();
    }
    int p = tsum[tid] - mysum;
    #pragma unroll
    for (int k = 0; k < 8; ++k) {
        if (t0 + k < NB) { lbase[t0 + k] = p; lcur[t0 + k] = p; }
        p += c8[k];
    }
    __syncthreads();
    for (int b = tid; b < NB; b += 256) {
        int cnt = lh[b];
        if (cnt) {
            int g = atomicAdd(&gCursor[b], cnt);
            lh[b] = g - lbase[b];
        }
    }
    __syncthreads();
    #pragma unroll
    for (int k = 0; k < 16; ++k) {
        if (c_[k] >= 0) {
            int b = c_[k] >> BSH;
            unsigned rem = (unsigned)(c_[k] & (BNODES - 1));
            int sp = atomicAdd(&lcur[b], 1);
            stage[sp] = make_uint2((unsigned)r_[k] | (rem << 20), __float_as_uint(w_[k]));
            sbuck[sp] = (unsigned short)b;
            if (pos != nullptr) pos[base + tid + 256 * k] = lh[b] + sp;
        }
    }
    __syncthreads();
    int nE = E - base;
    if (nE > CHUNK) nE = CHUNK;
    for (int j = tid; j < nE; j += 256)
        edata[lh[sbuck[j]] + j] = stage[j];
}

// row-sort scatter: key = row bucket, payload = pos | row_rem<<26
__global__ __launch_bounds__(256) void k_Rscatter(const int* __restrict__ row,
                                                  const int* __restrict__ pos,
                                                  int* __restrict__ rCursor,
                                                  uint* __restrict__ rrec,
                                                  int E, int NB) {
    __shared__ int lh[NB_MAX];
    __shared__ int lbase[NB_MAX];
    __shared__ int lcur[NB_MAX];
    __shared__ int tsum[256];
    __shared__ unsigned short sbuck[CHUNK];
    __shared__ uint stage[CHUNK];   // 16 KB
    const int tid = threadIdx.x;
    for (int i = tid; i < NB; i += 256) lh[i] = 0;
    __syncthreads();
    const int base = blockIdx.x * CHUNK;
    int r_[16];
    uint p_[16];
    #pragma unroll
    for (int k = 0; k < 16; ++k) {
        int e = base + tid + 256 * k;
        bool ok = e < E;
        r_[k] = ok ? row[e] : -1;
        p_[k] = ok ? (uint)pos[e] : 0u;
        if (ok) atomicAdd(&lh[r_[k] >> BSH], 1);
    }
    __syncthreads();
    const int t0 = tid * 8;
    int c8[8];
    int mysum = 0;
    #pragma unroll
    for (int k = 0; k < 8; ++k) {
        c8[k] = (t0 + k < NB) ? lh[t0 + k] : 0;
        mysum += c8[k];
    }
    tsum[tid] = mysum;
    __syncthreads();
    for (int off = 1; off < 256; off <<= 1) {
        int u = (tid >= off) ? tsum[tid - off] : 0;
        __syncthreads();
        tsum[tid] += u;
        __syncthreads();
    }
    int p = tsum[tid] - mysum;
    #pragma unroll
    for (int k = 0; k < 8; ++k) {
        if (t0 + k < NB) { lbase[t0 + k] = p; lcur[t0 + k] = p; }
        p += c8[k];
    }
    __syncthreads();
    for (int bb = tid; bb < NB; bb += 256) {
        int cnt = lh[bb];
        if (cnt) {
            int g = atomicAdd(&rCursor[bb], cnt);
            lh[bb] = g - lbase[bb];
        }
    }
    __syncthreads();
    #pragma unroll
    for (int k = 0; k < 16; ++k) {
        if (r_[k] >= 0) {
            int bb = r_[k] >> BSH;
            uint rem = (uint)(r_[k] & (BNODES - 1));
            int sp = atomicAdd(&lcur[bb], 1);
            stage[sp] = p_[k] | (rem << 26);
            sbuck[sp] = (unsigned short)bb;
        }
    }
    __syncthreads();
    int nE = E - base;
    if (nE > CHUNK) nE = CHUNK;
    for (int j = tid; j < nE; j += 256)
        rrec[lh[sbuck[j]] + j] = stage[j];
}

// sliced degree: dg[rem] partial in LDS, one global atomic per node per slice
__global__ __launch_bounds__(256) void k_deg(const int* __restrict__ gBase,
                                             const uint2* __restrict__ edata,
                                             float* __restrict__ deg, int N) {
    __shared__ float dg[BNODES];
    const int tid = threadIdx.x;
    if (tid < BNODES) dg[tid] = 0.f;
    __syncthreads();
    const int b = blockIdx.x;
    const int s = gBase[b], e = gBase[b + 1];
    for (int i = s + blockIdx.y * 256 + tid; i < e; i += 512) {
        uint2 ed = ntload_u2(&edata[i]);
        atomicAdd(&dg[ed.x >> 20], __uint_as_float(ed.y));
    }
    __syncthreads();
    int node = (b << BSH) + tid;
    if (tid < BNODES && node < N && dg[tid] != 0.f)
        atomicAdd(&deg[node], dg[tid]);
}

// h~ = rsqrt(deg+1) * (x @ W1) stored as bf16; also stores dinv (fp32).
__global__ __launch_bounds__(256) void k_h1(const float* __restrict__ x,
                                            const float* __restrict__ W1,
                                            const float* __restrict__ deg,
                                            float* __restrict__ dinv,
                                            __hip_bfloat16* __restrict__ hdb) {
    __shared__ float Ws[128 * DH];
    __shared__ float xs[16 * 132];
    const int t = threadIdx.x;
    const int node0 = blockIdx.x * 16;
    #pragma unroll
    for (int i = 0; i < 8; ++i) Ws[t + 256 * i] = W1[t + 256 * i];
    const float4* xg = (const float4*)(x + (size_t)node0 * 128);
    #pragma unroll
    for (int it = 0; it < 2; ++it) {
        int idx = t + 256 * it;
        int n = idx >> 5, k4 = idx & 31;
        float4 v = xg[n * 32 + k4];
        *(float4*)(&xs[n * 132 + k4 * 4]) = v;
    }
    __syncthreads();
    const int node = t >> 4, feat = t & 15;
    const float* xr = &xs[node * 132];
    float acc = 0.f;
    #pragma unroll 8
    for (int k = 0; k < 128; ++k) acc += xr[k] * Ws[k * DH + feat];
    const int v = node0 + node;
    const float di = rsqrtf(deg[v] + 1.0f);
    if (feat == 0) dinv[v] = di;
    hdb[(size_t)v * DH + feat] = __float2bfloat16(di * acc);
}

// ---------- pregather path ----------

// per row-bucket: stage 64 h-rows (2KB) in LDS; for edges whose col-slot lies
// in this phase's [slotLo,slotHi), write he[pos-slotLo] = h-row (2x16B stores)
__global__ __launch_bounds__(256) void k_hgather(const int* __restrict__ rBase,
                                                 const uint* __restrict__ rrec,
                                                 const uint* __restrict__ hdb32,
                                                 uint4* __restrict__ he16, int N,
                                                 const int* __restrict__ gBase,
                                                 int bLo, int bHi, int heCap) {
    __shared__ uint hs[BNODES * 8];   // 64 rows x 16 bf16
    const int tid = threadIdx.x;
    const int b = blockIdx.x;
    const int slotLo = gBase[bLo], slotHi = gBase[bHi];
    const int lim = N * 8 - b * 512;
    for (int i = tid; i < 512; i += 256)
        hs[i] = (i < lim) ? hdb32[(size_t)b * 512 + i] : 0u;
    __syncthreads();
    const int r0 = rBase[b], r1 = rBase[b + 1];
    for (int j = r0 + blockIdx.y * 256 + tid; j < r1; j += 512) {
        uint rec = rrec[j];
        int p = (int)(rec & 0x03FFFFFFu);
        if (p >= slotLo && p < slotHi) {
            int q = p - slotLo;
            if (q < heCap) {   // hard guard: no OOB even on phase imbalance
                const uint* hr = &hs[(rec >> 26) * 8];
                he16[(size_t)2 * q]     = make_uint4(hr[0], hr[1], hr[2], hr[3]);
                he16[(size_t)2 * q + 1] = make_uint4(hr[4], hr[5], hr[6], hr[7]);
            }
        }
    }
}

// layer-1 gather: FULLY COALESCED reads (edata + he), LDS atomic acc.
// 2 lanes/edge, 8 feats each; unroll-2 across j and j+128.
__global__ __launch_bounds__(256) void k_gather1_p(
    const int* __restrict__ gBase, const uint2* __restrict__ edata,
    const uint4* __restrict__ he16, float* __restrict__ partial,
    int bLo, int heCap) {
    __shared__ float acc[BNODES][DH + 1];
    const int tid = threadIdx.x;
    for (int i = tid; i < BNODES * (DH + 1); i += 256) ((float*)acc)[i] = 0.f;
    __syncthreads();
    const int b = bLo + blockIdx.x, sl = blockIdx.y;
    const int slotLo = gBase[bLo];
    const int s = gBase[b], e = gBase[b + 1];
    const int L = e - s;
    const int per = (L + NSL - 1) / NSL;
    const int s0 = s + sl * per;
    const int e0 = (s0 + per < e) ? (s0 + per) : e;
    const int hf = tid & 1, f0 = hf * 8;
    for (int jb = s0; jb < e0; jb += 256) {
        const int j0 = jb + (tid >> 1);
        const int j1 = j0 + 128;
        const bool v0 = (j0 < e0) && (j0 - slotLo < heCap);
        const bool v1 = (j1 < e0) && (j1 - slotLo < heCap);
        uint4 h0 = v0 ? he16[(size_t)2 * (j0 - slotLo) + hf] : make_uint4(0, 0, 0, 0);
        uint4 h1 = v1 ? he16[(size_t)2 * (j1 - slotLo) + hf] : make_uint4(0, 0, 0, 0);
        uint2 d0 = v0 ? edata[j0] : make_uint2(0u, 0u);
        uint2 d1 = v1 ? edata[j1] : make_uint2(0u, 0u);
        {
            const float w = __uint_as_float(d0.y);
            float* a = &acc[d0.x >> 20][f0];
            atomicAdd(a + 0, w * BFL(h0.x)); atomicAdd(a + 1, w * BFH(h0.x));
            atomicAdd(a + 2, w * BFL(h0.y)); atomicAdd(a + 3, w * BFH(h0.y));
            atomicAdd(a + 4, w * BFL(h0.z)); atomicAdd(a + 5, w * BFH(h0.z));
            atomicAdd(a + 6, w * BFL(h0.w)); atomicAdd(a + 7, w * BFH(h0.w));
        }
        {
            const float w = __uint_as_float(d1.y);
            float* a = &acc[d1.x >> 20][f0];
            atomicAdd(a + 0, w * BFL(h1.x)); atomicAdd(a + 1, w * BFH(h1.x));
            atomicAdd(a + 2, w * BFL(h1.y)); atomicAdd(a + 3, w * BFH(h1.y));
            atomicAdd(a + 4, w * BFL(h1.z)); atomicAdd(a + 5, w * BFH(h1.z));
            atomicAdd(a + 6, w * BFL(h1.w)); atomicAdd(a + 7, w * BFH(h1.w));
        }
    }
    __syncthreads();
    float* ps = partial + ((size_t)b * NSL + sl) * (DH * BNODES);
    for (int i = tid; i < DH * BNODES; i += 256)
        ps[i] = acc[i >> 4][i & 15];
}

// reduce slices + self-loop + bias + relu + dot(W2) -> q; init out;
// then scatter q into edge order: qe[pos] = q[row] (fire-and-forget 2B stores)
__global__ __launch_bounds__(256) void k_fin1_p(
    const float* __restrict__ partial, const float* __restrict__ dinv,
    const __hip_bfloat16* __restrict__ hdb, const float* __restrict__ b1,
    const float* __restrict__ W2, const float* __restrict__ b2,
    const int* __restrict__ rBase, const uint* __restrict__ rrec,
    __hip_bfloat16* __restrict__ qe, float* __restrict__ out, int N) {
    __shared__ float acc[BNODES][DH + 1];
    __shared__ float b1s[DH], W2s[DH];
    __shared__ __hip_bfloat16 qls[BNODES];
    const int tid = threadIdx.x;
    if (tid < DH) { b1s[tid] = b1[tid]; W2s[tid] = W2[tid]; }
    const int b = blockIdx.x;
    const float* ps = partial + (size_t)b * NSL * (DH * BNODES);
    for (int i = tid; i < DH * BNODES; i += 256) {
        float s = 0.f;
        #pragma unroll
        for (int sl = 0; sl < NSL; ++sl) s += ps[sl * (DH * BNODES) + i];
        acc[i >> 4][i & 15] = s;
    }
    __syncthreads();
    int node = (b << BSH) + tid;
    if (tid < BNODES && node < N) {
        float dc = dinv[node];
        const __hip_bfloat16* hs = hdb + (size_t)node * DH;
        float t = 0.f;
        #pragma unroll
        for (int f = 0; f < DH; ++f) {
            float hv = __bfloat162float(hs[f]);
            t += fmaxf(dc * (acc[tid][f] + hv) + b1s[f], 0.f) * W2s[f];
        }
        float qq = dc * t;
        qls[tid] = __float2bfloat16(qq);
        out[node] = b2[0] + dc * qq;    // bias + self-loop term of layer 2
    } else if (tid < BNODES) {
        qls[tid] = __float2bfloat16(0.f);
    }
    __syncthreads();
    const int r0 = rBase[b], r1 = rBase[b + 1];
    for (int j = r0 + tid; j < r1; j += 256) {
        uint rec = rrec[j];
        qe[rec & 0x03FFFFFFu] = qls[rec >> 26];
    }
}

// layer-2: coalesced edata + qe reads; a2[rem] LDS atomic;
// out[node] += dinv*a2 (1 global atomic per node per half)
__global__ __launch_bounds__(256) void k_gather2_p(
    const int* __restrict__ gBase, const uint2* __restrict__ edata,
    const float* __restrict__ dinv, const __hip_bfloat16* __restrict__ qe,
    float* __restrict__ out, int N) {
    __shared__ float a2[BNODES];
    const int tid = threadIdx.x;
    if (tid < BNODES) a2[tid] = 0.f;
    __syncthreads();
    const int b = blockIdx.x;
    const int s = gBase[b], e = gBase[b + 1];
    const int L = e - s;
    const int per = (L + 1) >> 1;
    const int s0 = s + blockIdx.y * per;
    const int e0 = (s0 + per < e) ? (s0 + per) : e;
    for (int i = s0 + tid; i < e0; i += 512) {
        const int i1 = i + 256;
        uint2 d0 = edata[i];
        uint2 d1 = (i1 < e0) ? edata[i1] : make_uint2(0u, 0u);
        float q0 = __bfloat162float(qe[i]);
        float q1 = (i1 < e0) ? __bfloat162float(qe[i1]) : 0.f;
        atomicAdd(&a2[d0.x >> 20], __uint_as_float(d0.y) * q0);
        atomicAdd(&a2[d1.x >> 20], __uint_as_float(d1.y) * q1);
    }
    __syncthreads();
    int node = (b << BSH) + tid;
    if (tid < BNODES && node < N && a2[tid] != 0.f)
        atomicAdd(&out[node], dinv[node] * a2[tid]);
}

// ---------- fallback path (R12 bodies, proven) ----------

__global__ __launch_bounds__(256) void k_gather1_fb(
    const int* __restrict__ gBase, const uint2* __restrict__ edata,
    const __hip_bfloat16* __restrict__ hdb, float* __restrict__ partial) {
    __shared__ float acc[BNODES][DH + 1];
    __shared__ uint2 se[SE_CAP];
    const int tid = threadIdx.x;
    for (int i = tid; i < BNODES * (DH + 1); i += 256) ((float*)acc)[i] = 0.f;
    const int b = blockIdx.x, sl = blockIdx.y;
    const int s = gBase[b], e = gBase[b + 1];
    const int L = e - s;
    const int per = (L + NSL_FB - 1) / NSL_FB;
    const int s0 = s + sl * per;
    const int e0 = (s0 + per < e) ? (s0 + per) : e;
    const int g = tid >> 3;
    const int f2 = tid & 7;
    const uint* __restrict__ hp = (const uint*)hdb;
    for (int c0 = s0; c0 < e0; c0 += SE_CAP) {
        const int len = ((e0 - c0) < SE_CAP) ? (e0 - c0) : SE_CAP;
        __syncthreads();
        for (int j = tid; j < len; j += 256) se[j] = ntload_u2(&edata[c0 + j]);
        __syncthreads();
        const int nfull = len & ~255;
        for (int j0 = 0; j0 < nfull; j0 += 256) {
            uint2 ed[8];
            uint hv[8];
            #pragma unroll
            for (int k = 0; k < 8; ++k) ed[k] = se[j0 + g + k * 32];
            #pragma unroll
            for (int k = 0; k < 8; ++k)
                hv[k] = hp[(size_t)(ed[k].x & 0xFFFFFu) * 8 + f2];
            #pragma unroll
            for (int k = 0; k < 8; ++k) {
                const float w = __uint_as_float(ed[k].y);
                const int rem = ed[k].x >> 20;
                atomicAdd(&acc[rem][2 * f2],     w * BFL(hv[k]));
                atomicAdd(&acc[rem][2 * f2 + 1], w * BFH(hv[k]));
            }
        }
        for (int j = nfull + g; j < len; j += 32) {
            const uint2 ed = se[j];
            const uint hv = hp[(size_t)(ed.x & 0xFFFFFu) * 8 + f2];
            const float w = __uint_as_float(ed.y);
            const int rem = ed.x >> 20;
            atomicAdd(&acc[rem][2 * f2],     w * BFL(hv));
            atomicAdd(&acc[rem][2 * f2 + 1], w * BFH(hv));
        }
    }
    __syncthreads();
    float* ps = partial + ((size_t)b * NSL_FB + sl) * (DH * BNODES);
    for (int i = tid; i < DH * BNODES; i += 256)
        ps[i] = acc[i >> 4][i & 15];
}

__global__ __launch_bounds__(256) void k_fin1_fb(
    const float* __restrict__ partial, const float* __restrict__ dinv,
    const __hip_bfloat16* __restrict__ hdb, const float* __restrict__ b1,
    const float* __restrict__ W2, const float* __restrict__ b2,
    __hip_bfloat16* __restrict__ qb, float* __restrict__ out, int N) {
    __shared__ float acc[BNODES][DH + 1];
    __shared__ float b1s[DH], W2s[DH];
    const int tid = threadIdx.x;
    if (tid < DH) { b1s[tid] = b1[tid]; W2s[tid] = W2[tid]; }
    const int b = blockIdx.x;
    const float* ps = partial + (size_t)b * NSL_FB * (DH * BNODES);
    for (int i = tid; i < DH * BNODES; i += 256) {
        float s = 0.f;
        #pragma unroll
        for (int sl = 0; sl < NSL_FB; ++sl) s += ps[sl * (DH * BNODES) + i];
        acc[i >> 4][i & 15] = s;
    }
    __syncthreads();
    int node = (b << BSH) + tid;
    if (tid < BNODES && node < N) {
        float dc = dinv[node];
        const __hip_bfloat16* hs = hdb + (size_t)node * DH;
        float t = 0.f;
        #pragma unroll
        for (int f = 0; f < DH; ++f) {
            float hv = __bfloat162float(hs[f]);
            t += fmaxf(dc * (acc[tid][f] + hv) + b1s[f], 0.f) * W2s[f];
        }
        float qq = dc * t;
        qb[node] = __float2bfloat16(qq);
        out[node] = b2[0] + dc * qq;
    }
}

__global__ __launch_bounds__(256) void k_gather2_fb(
    const int* __restrict__ gBase, const uint2* __restrict__ edata,
    const float* __restrict__ dinv, const __hip_bfloat16* __restrict__ qb,
    float* __restrict__ out, int N) {
    __shared__ float a2[BNODES];
    __shared__ uint2 se[SE2_CAP];
    const int tid = threadIdx.x;
    if (tid < BNODES) a2[tid] = 0.f;
    const int b = blockIdx.x;
    const int s = gBase[b], e = gBase[b + 1];
    const int L = e - s;
    const int per = (L + 1) >> 1;
    const int s0 = s + blockIdx.y * per;
    const int e0 = (s0 + per < e) ? (s0 + per) : e;
    const ushort* __restrict__ qp = (const ushort*)qb;
    for (int c0 = s0; c0 < e0; c0 += SE2_CAP) {
        const int len = ((e0 - c0) < SE2_CAP) ? (e0 - c0) : SE2_CAP;
        __syncthreads();
        for (int j = tid; j < len; j += 256) se[j] = ntload_u2(&edata[c0 + j]);
        __syncthreads();
        for (int j = tid; j < len; j += 256) {
            const uint2 ed = se[j];
            const float q = __uint_as_float((uint)qp[ed.x & 0xFFFFFu] << 16);
            atomicAdd(&a2[ed.x >> 20], __uint_as_float(ed.y) * q);
        }
    }
    __syncthreads();
    int node = (b << BSH) + tid;
    if (tid < BNODES && node < N && a2[tid] != 0.f)
        atomicAdd(&out[node], dinv[node] * a2[tid]);
}

// ---------- launcher ----------

extern "C" void kernel_launch(void* const* d_in, const int* in_sizes, int n_in,
                              void* d_out, int out_size, void* d_ws, size_t ws_size,
                              hipStream_t stream) {
    const float* x  = (const float*)d_in[0];
    const int*   ei = (const int*)d_in[1];
    const float* ew = (const float*)d_in[2];
    const float* W1 = (const float*)d_in[3];
    const float* b1 = (const float*)d_in[4];
    const float* W2 = (const float*)d_in[5];
    const float* b2 = (const float*)d_in[6];
    float* out = (float*)d_out;

    const int N = in_sizes[0] / 128;       // 100000
    const int E = in_sizes[2];             // 3200000
    const int* row = ei;
    const int* col = ei + E;
    const int NB = (N + BNODES - 1) >> BSH;   // 1563

    const int hblocks = (E + HCHUNK - 1) / HCHUNK;  // 391
    const int sblocks = (E + CHUNK - 1) / CHUNK;    // 782

    // ---- pregather layout (all fields 16B-multiples; packed) ----
    const int NBp = NB_MAX;                                // 1568
    char* base = (char*)d_ws;
    size_t off = 0;
    int*   gCnt    = (int*)(base + off);   off += (size_t)NBp * 4;
    int*   rCnt    = (int*)(base + off);   off += (size_t)NBp * 4;
    float* deg     = (float*)(base + off); off += (size_t)N * 4;
    int*   gBase   = (int*)(base + off);   off += (size_t)NBp * 4;
    int*   rBase   = (int*)(base + off);   off += (size_t)NBp * 4;
    int*   gCursor = (int*)(base + off);   off += (size_t)NBp * 4;
    int*   rCursor = (int*)(base + off);   off += (size_t)NBp * 4;
    float* dinv    = (float*)(base + off); off += (size_t)N * 4;
    __hip_bfloat16* hdb = (__hip_bfloat16*)(base + off); off += (size_t)16 * N * 2;
    __hip_bfloat16* qe  = (__hip_bfloat16*)(base + off); off += (size_t)E * 2;
    uint*  rrec    = (uint*)(base + off);  off += (size_t)E * 4;
    float* partial = (float*)(base + off); off += (size_t)NB * NSL * (DH * BNODES) * 4;
    uint2* edata   = (uint2*)(base + off); off += (size_t)E * 8;
    int*   pos     = (int*)(base + off);               // overlaid in he region
    uint4* he16    = (uint4*)(base + off);
    const size_t base_need = off;

    int nph = 0;
    int heCap = 0;
    const int cands[4] = {1, 2, 4, 8};
    for (int c = 0; c < 4; ++c) {
        int cap = E / cands[c] + HESLACK;
        if (base_need + (size_t)cap * 32 <= ws_size) { nph = cands[c]; heCap = cap; break; }
    }

    if (nph > 0) {
        // ---- pregather path ----
        hipMemsetAsync(gCnt, 0, ((size_t)2 * NBp + N) * sizeof(int), stream);
        k_hist2<<<hblocks, 256, 0, stream>>>(row, col, gCnt, rCnt, E, NB);
        k_Ascan<<<1, 1024, 0, stream>>>(gCnt, gBase, gCursor, NB, E);
        k_Ascan<<<1, 1024, 0, stream>>>(rCnt, rBase, rCursor, NB, E);
        k_Ascatter<<<sblocks, 256, 0, stream>>>(row, col, ew, gCursor, edata, pos, E, NB);
        k_Rscatter<<<sblocks, 256, 0, stream>>>(row, pos, rCursor, rrec, E, NB);
        k_deg<<<dim3(NB, 2), 256, 0, stream>>>(gBase, edata, deg, N);
        k_h1<<<N / 16, 256, 0, stream>>>(x, W1, deg, dinv, hdb);
        for (int ph = 0; ph < nph; ++ph) {
            int bLo = (int)((long long)NB * ph / nph);
            int bHi = (int)((long long)NB * (ph + 1) / nph);
            k_hgather<<<dim3(NB, 2), 256, 0, stream>>>(rBase, rrec, (const uint*)hdb,
                                                       he16, N, gBase, bLo, bHi, heCap);
            k_gather1_p<<<dim3(bHi - bLo, NSL), 256, 0, stream>>>(gBase, edata, he16,
                                                                  partial, bLo, heCap);
        }
        k_fin1_p<<<NB, 256, 0, stream>>>(partial, dinv, hdb, b1, W2, b2,
                                         rBase, rrec, qe, out, N);
        k_gather2_p<<<dim3(NB, 2), 256, 0, stream>>>(gBase, edata, dinv, qe, out, N);
    } else {
        // ---- fallback: exact R12 layout & schedule (proven ~532us) ----
        const int NBf = (NB + 3) & ~3;
        int* fgCnt    = (int*)d_ws;
        float* fdeg   = (float*)(fgCnt + NBf);
        int* fgBase   = (int*)(fdeg + N);
        int* fgCursor = fgBase + NBf;
        float* fdinv  = (float*)(fgCursor + NBf);
        __hip_bfloat16* fhdb = (__hip_bfloat16*)(fdinv + N);
        __hip_bfloat16* fqb  = fhdb + (size_t)16 * N;
        uintptr_t pp = (uintptr_t)(fqb + N);
        pp = (pp + 15) & ~(uintptr_t)15;
        float* fpartial = (float*)pp;
        uintptr_t ep = (uintptr_t)(fpartial + (size_t)NB * NSL_FB * (DH * BNODES));
        ep = (ep + 15) & ~(uintptr_t)15;
        uint2* fedata = (uint2*)ep;

        hipMemsetAsync(fgCnt, 0, ((size_t)NBf + N) * sizeof(int), stream);
        k_Ahist<<<hblocks, 256, 0, stream>>>(col, fgCnt, E, NB);
        k_Ascan<<<1, 1024, 0, stream>>>(fgCnt, fgBase, fgCursor, NB, E);
        k_Ascatter<<<sblocks, 256, 0, stream>>>(row, col, ew, fgCursor, fedata, nullptr, E, NB);
        k_deg<<<dim3(NB, 2), 256, 0, stream>>>(fgBase, fedata, fdeg, N);
        k_h1<<<N / 16, 256, 0, stream>>>(x, W1, fdeg, fdinv, fhdb);
        k_gather1_fb<<<dim3(NB, NSL_FB), 256, 0, stream>>>(fgBase, fedata, fhdb, fpartial);
        k_fin1_fb<<<NB, 256, 0, stream>>>(fpartial, fdinv, fhdb, b1, W2, b2, fqb, out, N);
        k_gather2_fb<<<dim3(NB, 2), 256, 0, stream>>>(fgBase, fedata, fdinv, fqb, out, N);
    }
}

// Round 7
// 698.682 us; speedup vs baseline: 1.0592x; 1.0592x over previous
//
#include <hip/hip_runtime.h>
#include <hip/hip_bf16.h>

// SectorGCN R14: R13 dual-sort pregather + STAGED read-back.
// R13 forensics: scattered stores (k_hgather, 51MB/phase) ~20us = fast;
// coalesced-in-loop reads (k_gather1_p, VGPR=12) = 327us at 196 GB/s = the
// wall. Pattern across R7-R13: dense staging-copy loops stream at ~1.2 TB/s
// (R11 <2> arm: staged edata + all atomics = 22us); loads inside the consume
// loop serialize (compiler: load->waitcnt(0)->use at tiny VGPR budgets).
// Fix: gather1_p/gather2_p stage 512/1024-edge chunks of he/edata/qe into LDS
// with bulk copies, consume from LDS only. Everything else = R13.
// N=100000, E=3200000, d_in=128, d_h=16.

#define DH 16
#define BSH 6
#define BNODES 64
#define NB_MAX 1568
#define CHUNK 4096        // scatter chunk
#define HCHUNK 8192       // hist chunk
#define NSL 2             // pregather-path slices
#define NSL_FB 4          // fallback slices
#define CH1 512           // gather1 staged edges per chunk
#define CH2 1024          // gather2 staged edges per chunk
#define SE_CAP 768        // fallback gather1 staged edges
#define SE2_CAP 1280      // fallback gather2 staged edges
#define HESLACK 65536     // he capacity slack (slots)

#define BFL(u) __uint_as_float((u) << 16)
#define BFH(u) __uint_as_float((u) & 0xFFFF0000u)

typedef unsigned int u32x2 __attribute__((ext_vector_type(2)));
typedef unsigned int u32x4 __attribute__((ext_vector_type(4)));

static __device__ __forceinline__ uint2 ntload_u2(const uint2* p) {
    u32x2 v = __builtin_nontemporal_load((const u32x2*)p);
    return make_uint2(v.x, v.y);
}
static __device__ __forceinline__ uint4 ntload_u4(const uint4* p) {
    u32x4 v = __builtin_nontemporal_load((const u32x4*)p);
    return make_uint4(v.x, v.y, v.z, v.w);
}

// ---------- shared kernels ----------

// histogram of BOTH col-buckets and row-buckets in one pass (pregather path)
__global__ __launch_bounds__(256) void k_hist2(const int* __restrict__ row,
                                               const int* __restrict__ col,
                                               int* __restrict__ gCnt,
                                               int* __restrict__ rCnt, int E, int NB) {
    __shared__ int lc[NB_MAX];
    __shared__ int lr[NB_MAX];
    const int tid = threadIdx.x;
    for (int i = tid; i < NB; i += 256) { lc[i] = 0; lr[i] = 0; }
    __syncthreads();
    const int base = blockIdx.x * HCHUNK;
    #pragma unroll
    for (int k = 0; k < 32; ++k) {
        int e = base + tid + 256 * k;
        if (e < E) {
            atomicAdd(&lc[col[e] >> BSH], 1);
            atomicAdd(&lr[row[e] >> BSH], 1);
        }
    }
    __syncthreads();
    for (int i = tid; i < NB; i += 256) {
        if (lc[i]) atomicAdd(&gCnt[i], lc[i]);
        if (lr[i]) atomicAdd(&rCnt[i], lr[i]);
    }
}

// col-only histogram (fallback path)
__global__ __launch_bounds__(256) void k_Ahist(const int* __restrict__ col,
                                               int* __restrict__ gCnt, int E, int NB) {
    __shared__ int lh[NB_MAX];
    const int tid = threadIdx.x;
    for (int i = tid; i < NB; i += 256) lh[i] = 0;
    __syncthreads();
    const int base = blockIdx.x * HCHUNK;
    #pragma unroll
    for (int k = 0; k < 32; ++k) {
        int e = base + tid + 256 * k;
        if (e < E) atomicAdd(&lh[col[e] >> BSH], 1);
    }
    __syncthreads();
    for (int i = tid; i < NB; i += 256) {
        int v = lh[i];
        if (v) atomicAdd(&gCnt[i], v);
    }
}

// exclusive scan of cnt[NB], NB <= 2048 (2 elems/thread)
__global__ __launch_bounds__(1024) void k_Ascan(const int* __restrict__ cnt,
                                                int* __restrict__ basep,
                                                int* __restrict__ cursor,
                                                int NB, int E) {
    __shared__ int s[1024];
    const int t = threadIdx.x;
    const int i0 = 2 * t, i1 = 2 * t + 1;
    int a = (i0 < NB) ? cnt[i0] : 0;
    int b = (i1 < NB) ? cnt[i1] : 0;
    int v = a + b;
    s[t] = v;
    __syncthreads();
    for (int off = 1; off < 1024; off <<= 1) {
        int u = (t >= off) ? s[t - off] : 0;
        __syncthreads();
        s[t] += u;
        __syncthreads();
    }
    int ex = s[t] - v;
    if (i0 < NB) { basep[i0] = ex;     cursor[i0] = ex; }
    if (i1 < NB) { basep[i1] = ex + a; cursor[i1] = ex + a; }
    if (t == 0) basep[NB] = E;
}

// col-sort scatter; optionally records pos[e] = destination slot of edge e
__global__ __launch_bounds__(256) void k_Ascatter(const int* __restrict__ row,
                                                  const int* __restrict__ col,
                                                  const float* __restrict__ ew,
                                                  int* __restrict__ gCursor,
                                                  uint2* __restrict__ edata,
                                                  int* __restrict__ pos,
                                                  int E, int NB) {
    __shared__ int lh[NB_MAX];      // counts, then (globalRun - localBase)
    __shared__ int lbase[NB_MAX];
    __shared__ int lcur[NB_MAX];
    __shared__ int tsum[256];
    __shared__ unsigned short sbuck[CHUNK];
    __shared__ uint2 stage[CHUNK];  // 32 KB
    const int tid = threadIdx.x;
    for (int i = tid; i < NB; i += 256) lh[i] = 0;
    __syncthreads();
    const int base = blockIdx.x * CHUNK;
    int r_[16], c_[16];
    float w_[16];
    #pragma unroll
    for (int k = 0; k < 16; ++k) {
        int e = base + tid + 256 * k;
        bool ok = e < E;
        c_[k] = ok ? col[e] : -1;
        r_[k] = ok ? row[e] : 0;
        w_[k] = ok ? ew[e] : 0.f;
        if (ok) atomicAdd(&lh[c_[k] >> BSH], 1);
    }
    __syncthreads();
    const int t0 = tid * 8;
    int c8[8];
    int mysum = 0;
    #pragma unroll
    for (int k = 0; k < 8; ++k) {
        c8[k] = (t0 + k < NB) ? lh[t0 + k] : 0;
        mysum += c8[k];
    }
    tsum[tid] = mysum;
    __syncthreads();
    for (int off = 1; off < 256; off <<= 1) {
        int u = (tid >= off) ? tsum[tid - off] : 0;
        __syncthreads();
        tsum[tid] += u;
        __syncthreads();
    }
    int p = tsum[tid] - mysum;
    #pragma unroll
    for (int k = 0; k < 8; ++k) {
        if (t0 + k < NB) { lbase[t0 + k] = p; lcur[t0 + k] = p; }
        p += c8[k];
    }
    __syncthreads();
    for (int b = tid; b < NB; b += 256) {
        int cnt = lh[b];
        if (cnt) {
            int g = atomicAdd(&gCursor[b], cnt);
            lh[b] = g - lbase[b];
        }
    }
    __syncthreads();
    #pragma unroll
    for (int k = 0; k < 16; ++k) {
        if (c_[k] >= 0) {
            int b = c_[k] >> BSH;
            unsigned rem = (unsigned)(c_[k] & (BNODES - 1));
            int sp = atomicAdd(&lcur[b], 1);
            stage[sp] = make_uint2((unsigned)r_[k] | (rem << 20), __float_as_uint(w_[k]));
            sbuck[sp] = (unsigned short)b;
            if (pos != nullptr) pos[base + tid + 256 * k] = lh[b] + sp;
        }
    }
    __syncthreads();
    int nE = E - base;
    if (nE > CHUNK) nE = CHUNK;
    for (int j = tid; j < nE; j += 256)
        edata[lh[sbuck[j]] + j] = stage[j];
}

// row-sort scatter: key = row bucket, payload = pos | row_rem<<26
__global__ __launch_bounds__(256) void k_Rscatter(const int* __restrict__ row,
                                                  const int* __restrict__ pos,
                                                  int* __restrict__ rCursor,
                                                  uint* __restrict__ rrec,
                                                  int E, int NB) {
    __shared__ int lh[NB_MAX];
    __shared__ int lbase[NB_MAX];
    __shared__ int lcur[NB_MAX];
    __shared__ int tsum[256];
    __shared__ unsigned short sbuck[CHUNK];
    __shared__ uint stage[CHUNK];   // 16 KB
    const int tid = threadIdx.x;
    for (int i = tid; i < NB; i += 256) lh[i] = 0;
    __syncthreads();
    const int base = blockIdx.x * CHUNK;
    int r_[16];
    uint p_[16];
    #pragma unroll
    for (int k = 0; k < 16; ++k) {
        int e = base + tid + 256 * k;
        bool ok = e < E;
        r_[k] = ok ? row[e] : -1;
        p_[k] = ok ? (uint)pos[e] : 0u;
        if (ok) atomicAdd(&lh[r_[k] >> BSH], 1);
    }
    __syncthreads();
    const int t0 = tid * 8;
    int c8[8];
    int mysum = 0;
    #pragma unroll
    for (int k = 0; k < 8; ++k) {
        c8[k] = (t0 + k < NB) ? lh[t0 + k] : 0;
        mysum += c8[k];
    }
    tsum[tid] = mysum;
    __syncthreads();
    for (int off = 1; off < 256; off <<= 1) {
        int u = (tid >= off) ? tsum[tid - off] : 0;
        __syncthreads();
        tsum[tid] += u;
        __syncthreads();
    }
    int p = tsum[tid] - mysum;
    #pragma unroll
    for (int k = 0; k < 8; ++k) {
        if (t0 + k < NB) { lbase[t0 + k] = p; lcur[t0 + k] = p; }
        p += c8[k];
    }
    __syncthreads();
    for (int bb = tid; bb < NB; bb += 256) {
        int cnt = lh[bb];
        if (cnt) {
            int g = atomicAdd(&rCursor[bb], cnt);
            lh[bb] = g - lbase[bb];
        }
    }
    __syncthreads();
    #pragma unroll
    for (int k = 0; k < 16; ++k) {
        if (r_[k] >= 0) {
            int bb = r_[k] >> BSH;
            uint rem = (uint)(r_[k] & (BNODES - 1));
            int sp = atomicAdd(&lcur[bb], 1);
            stage[sp] = p_[k] | (rem << 26);
            sbuck[sp] = (unsigned short)bb;
        }
    }
    __syncthreads();
    int nE = E - base;
    if (nE > CHUNK) nE = CHUNK;
    for (int j = tid; j < nE; j += 256)
        rrec[lh[sbuck[j]] + j] = stage[j];
}

// sliced degree: dg[rem] partial in LDS, one global atomic per node per slice
__global__ __launch_bounds__(256) void k_deg(const int* __restrict__ gBase,
                                             const uint2* __restrict__ edata,
                                             float* __restrict__ deg, int N) {
    __shared__ float dg[BNODES];
    const int tid = threadIdx.x;
    if (tid < BNODES) dg[tid] = 0.f;
    __syncthreads();
    const int b = blockIdx.x;
    const int s = gBase[b], e = gBase[b + 1];
    for (int i = s + blockIdx.y * 256 + tid; i < e; i += 512) {
        uint2 ed = ntload_u2(&edata[i]);
        atomicAdd(&dg[ed.x >> 20], __uint_as_float(ed.y));
    }
    __syncthreads();
    int node = (b << BSH) + tid;
    if (tid < BNODES && node < N && dg[tid] != 0.f)
        atomicAdd(&deg[node], dg[tid]);
}

// h~ = rsqrt(deg+1) * (x @ W1) stored as bf16; also stores dinv (fp32).
__global__ __launch_bounds__(256) void k_h1(const float* __restrict__ x,
                                            const float* __restrict__ W1,
                                            const float* __restrict__ deg,
                                            float* __restrict__ dinv,
                                            __hip_bfloat16* __restrict__ hdb) {
    __shared__ float Ws[128 * DH];
    __shared__ float xs[16 * 132];
    const int t = threadIdx.x;
    const int node0 = blockIdx.x * 16;
    #pragma unroll
    for (int i = 0; i < 8; ++i) Ws[t + 256 * i] = W1[t + 256 * i];
    const float4* xg = (const float4*)(x + (size_t)node0 * 128);
    #pragma unroll
    for (int it = 0; it < 2; ++it) {
        int idx = t + 256 * it;
        int n = idx >> 5, k4 = idx & 31;
        float4 v = xg[n * 32 + k4];
        *(float4*)(&xs[n * 132 + k4 * 4]) = v;
    }
    __syncthreads();
    const int node = t >> 4, feat = t & 15;
    const float* xr = &xs[node * 132];
    float acc = 0.f;
    #pragma unroll 8
    for (int k = 0; k < 128; ++k) acc += xr[k] * Ws[k * DH + feat];
    const int v = node0 + node;
    const float di = rsqrtf(deg[v] + 1.0f);
    if (feat == 0) dinv[v] = di;
    hdb[(size_t)v * DH + feat] = __float2bfloat16(di * acc);
}

// ---------- pregather path ----------

// per row-bucket: stage 64 h-rows (2KB) in LDS; for edges whose col-slot lies
// in this phase's [slotLo,slotHi), write he[pos-slotLo] = h-row (2x16B stores)
__global__ __launch_bounds__(256) void k_hgather(const int* __restrict__ rBase,
                                                 const uint* __restrict__ rrec,
                                                 const uint* __restrict__ hdb32,
                                                 uint4* __restrict__ he16, int N,
                                                 const int* __restrict__ gBase,
                                                 int bLo, int bHi, int heCap) {
    __shared__ uint hs[BNODES * 8];   // 64 rows x 16 bf16
    const int tid = threadIdx.x;
    const int b = blockIdx.x;
    const int slotLo = gBase[bLo], slotHi = gBase[bHi];
    const int lim = N * 8 - b * 512;
    for (int i = tid; i < 512; i += 256)
        hs[i] = (i < lim) ? hdb32[(size_t)b * 512 + i] : 0u;
    __syncthreads();
    const int r0 = rBase[b], r1 = rBase[b + 1];
    for (int j = r0 + blockIdx.y * 256 + tid; j < r1; j += 512) {
        uint rec = rrec[j];
        int p = (int)(rec & 0x03FFFFFFu);
        if (p >= slotLo && p < slotHi) {
            int q = p - slotLo;
            if (q < heCap) {   // hard guard: no OOB even on phase imbalance
                const uint* hr = &hs[(rec >> 26) * 8];
                he16[(size_t)2 * q]     = make_uint4(hr[0], hr[1], hr[2], hr[3]);
                he16[(size_t)2 * q + 1] = make_uint4(hr[4], hr[5], hr[6], hr[7]);
            }
        }
    }
}

// layer-1 gather, R14: STAGED read-back. Per 512-edge chunk: bulk-copy
// edata (4KB) + he (16KB) into LDS with dense coalesced loops (the proven
// TB/s idiom), then consume from LDS: 2 lanes/edge x 8 feats, LDS atomic acc.
__global__ __launch_bounds__(256) void k_gather1_p(
    const int* __restrict__ gBase, const uint2* __restrict__ edata,
    const uint4* __restrict__ he16, float* __restrict__ partial,
    int bLo, int heCap) {
    __shared__ float acc[BNODES][DH + 1];   // 4.3 KB
    __shared__ uint2 se[CH1];               // 4 KB
    __shared__ uint4 sh[2 * CH1];           // 16 KB
    const int tid = threadIdx.x;
    for (int i = tid; i < BNODES * (DH + 1); i += 256) ((float*)acc)[i] = 0.f;
    const int b = bLo + blockIdx.x, sl = blockIdx.y;
    const int slotLo = gBase[bLo];
    const int s = gBase[b], e = gBase[b + 1];
    const int L = e - s;
    const int per = (L + NSL - 1) / NSL;
    const int s0 = s + sl * per;
    const int e0 = (s0 + per < e) ? (s0 + per) : e;
    const int hf = tid & 1, f0 = hf * 8;
    const int hCap2 = 2 * heCap;

    for (int c0 = s0; c0 < e0; c0 += CH1) {
        const int len = ((e0 - c0) < CH1) ? (e0 - c0) : CH1;
        __syncthreads();   // acc-init / previous chunk consumed
        for (int i = tid; i < len; i += 256)
            se[i] = ntload_u2(&edata[c0 + i]);
        const int hb = 2 * (c0 - slotLo);
        const int hlen = 2 * len;
        for (int i = tid; i < hlen; i += 256) {
            int gi = hb + i;
            sh[i] = (gi < hCap2) ? ntload_u4(&he16[gi]) : make_uint4(0, 0, 0, 0);
        }
        __syncthreads();
        #pragma unroll
        for (int k = 0; k < CH1 / 128; ++k) {      // 4 edges per thread-pair
            const int idx = (tid >> 1) + k * 128;
            if (idx < len) {
                const uint2 d = se[idx];
                const uint4 h = sh[2 * idx + hf];
                const float w = __uint_as_float(d.y);
                float* a = &acc[d.x >> 20][f0];
                atomicAdd(a + 0, w * BFL(h.x)); atomicAdd(a + 1, w * BFH(h.x));
                atomicAdd(a + 2, w * BFL(h.y)); atomicAdd(a + 3, w * BFH(h.y));
                atomicAdd(a + 4, w * BFL(h.z)); atomicAdd(a + 5, w * BFH(h.z));
                atomicAdd(a + 6, w * BFL(h.w)); atomicAdd(a + 7, w * BFH(h.w));
            }
        }
    }
    __syncthreads();
    float* ps = partial + ((size_t)b * NSL + sl) * (DH * BNODES);
    for (int i = tid; i < DH * BNODES; i += 256)
        ps[i] = acc[i >> 4][i & 15];
}

// reduce slices + self-loop + bias + relu + dot(W2) -> q; init out;
// then scatter q into edge order: qe[pos] = q[row] (fire-and-forget 2B stores)
__global__ __launch_bounds__(256) void k_fin1_p(
    const float* __restrict__ partial, const float* __restrict__ dinv,
    const __hip_bfloat16* __restrict__ hdb, const float* __restrict__ b1,
    const float* __restrict__ W2, const float* __restrict__ b2,
    const int* __restrict__ rBase, const uint* __restrict__ rrec,
    __hip_bfloat16* __restrict__ qe, float* __restrict__ out, int N) {
    __shared__ float acc[BNODES][DH + 1];
    __shared__ float b1s[DH], W2s[DH];
    __shared__ __hip_bfloat16 qls[BNODES];
    const int tid = threadIdx.x;
    if (tid < DH) { b1s[tid] = b1[tid]; W2s[tid] = W2[tid]; }
    const int b = blockIdx.x;
    const float* ps = partial + (size_t)b * NSL * (DH * BNODES);
    for (int i = tid; i < DH * BNODES; i += 256) {
        float s = 0.f;
        #pragma unroll
        for (int sl = 0; sl < NSL; ++sl) s += ps[sl * (DH * BNODES) + i];
        acc[i >> 4][i & 15] = s;
    }
    __syncthreads();
    int node = (b << BSH) + tid;
    if (tid < BNODES && node < N) {
        float dc = dinv[node];
        const __hip_bfloat16* hs = hdb + (size_t)node * DH;
        float t = 0.f;
        #pragma unroll
        for (int f = 0; f < DH; ++f) {
            float hv = __bfloat162float(hs[f]);
            t += fmaxf(dc * (acc[tid][f] + hv) + b1s[f], 0.f) * W2s[f];
        }
        float qq = dc * t;
        qls[tid] = __float2bfloat16(qq);
        out[node] = b2[0] + dc * qq;    // bias + self-loop term of layer 2
    } else if (tid < BNODES) {
        qls[tid] = __float2bfloat16(0.f);
    }
    __syncthreads();
    const int r0 = rBase[b], r1 = rBase[b + 1];
    for (int j = r0 + tid; j < r1; j += 256) {
        uint rec = rrec[j];
        qe[rec & 0x03FFFFFFu] = qls[rec >> 26];
    }
}

// layer-2, R14: STAGED read-back (edata + qe chunks in LDS), a2[rem] LDS
// atomic; out[node] += dinv*a2 (1 global atomic per node per half)
__global__ __launch_bounds__(256) void k_gather2_p(
    const int* __restrict__ gBase, const uint2* __restrict__ edata,
    const float* __restrict__ dinv, const __hip_bfloat16* __restrict__ qe,
    float* __restrict__ out, int N) {
    __shared__ float a2[BNODES];
    __shared__ uint2 se[CH2];      // 8 KB
    __shared__ ushort sq[CH2];     // 2 KB
    const int tid = threadIdx.x;
    if (tid < BNODES) a2[tid] = 0.f;
    const int b = blockIdx.x;
    const int s = gBase[b], e = gBase[b + 1];
    const int L = e - s;
    const int per = (L + 1) >> 1;
    const int s0 = s + blockIdx.y * per;
    const int e0 = (s0 + per < e) ? (s0 + per) : e;
    const ushort* __restrict__ qp = (const ushort*)qe;

    for (int c0 = s0; c0 < e0; c0 += CH2) {
        const int len = ((e0 - c0) < CH2) ? (e0 - c0) : CH2;
        __syncthreads();
        for (int i = tid; i < len; i += 256) se[i] = ntload_u2(&edata[c0 + i]);
        for (int i = tid; i < len; i += 256) sq[i] = qp[c0 + i];
        __syncthreads();
        #pragma unroll
        for (int k = 0; k < CH2 / 256; ++k) {
            const int idx = tid + k * 256;
            if (idx < len) {
                const uint2 d = se[idx];
                const float q = __uint_as_float((uint)sq[idx] << 16);
                atomicAdd(&a2[d.x >> 20], __uint_as_float(d.y) * q);
            }
        }
    }
    __syncthreads();
    int node = (b << BSH) + tid;
    if (tid < BNODES && node < N && a2[tid] != 0.f)
        atomicAdd(&out[node], dinv[node] * a2[tid]);
}

// ---------- fallback path (R12 bodies, proven) ----------

__global__ __launch_bounds__(256) void k_gather1_fb(
    const int* __restrict__ gBase, const uint2* __restrict__ edata,
    const __hip_bfloat16* __restrict__ hdb, float* __restrict__ partial) {
    __shared__ float acc[BNODES][DH + 1];
    __shared__ uint2 se[SE_CAP];
    const int tid = threadIdx.x;
    for (int i = tid; i < BNODES * (DH + 1); i += 256) ((float*)acc)[i] = 0.f;
    const int b = blockIdx.x, sl = blockIdx.y;
    const int s = gBase[b], e = gBase[b + 1];
    const int L = e - s;
    const int per = (L + NSL_FB - 1) / NSL_FB;
    const int s0 = s + sl * per;
    const int e0 = (s0 + per < e) ? (s0 + per) : e;
    const int g = tid >> 3;
    const int f2 = tid & 7;
    const uint* __restrict__ hp = (const uint*)hdb;
    for (int c0 = s0; c0 < e0; c0 += SE_CAP) {
        const int len = ((e0 - c0) < SE_CAP) ? (e0 - c0) : SE_CAP;
        __syncthreads();
        for (int j = tid; j < len; j += 256) se[j] = ntload_u2(&edata[c0 + j]);
        __syncthreads();
        const int nfull = len & ~255;
        for (int j0 = 0; j0 < nfull; j0 += 256) {
            uint2 ed[8];
            uint hv[8];
            #pragma unroll
            for (int k = 0; k < 8; ++k) ed[k] = se[j0 + g + k * 32];
            #pragma unroll
            for (int k = 0; k < 8; ++k)
                hv[k] = hp[(size_t)(ed[k].x & 0xFFFFFu) * 8 + f2];
            #pragma unroll
            for (int k = 0; k < 8; ++k) {
                const float w = __uint_as_float(ed[k].y);
                const int rem = ed[k].x >> 20;
                atomicAdd(&acc[rem][2 * f2],     w * BFL(hv[k]));
                atomicAdd(&acc[rem][2 * f2 + 1], w * BFH(hv[k]));
            }
        }
        for (int j = nfull + g; j < len; j += 32) {
            const uint2 ed = se[j];
            const uint hv = hp[(size_t)(ed.x & 0xFFFFFu) * 8 + f2];
            const float w = __uint_as_float(ed.y);
            const int rem = ed.x >> 20;
            atomicAdd(&acc[rem][2 * f2],     w * BFL(hv));
            atomicAdd(&acc[rem][2 * f2 + 1], w * BFH(hv));
        }
    }
    __syncthreads();
    float* ps = partial + ((size_t)b * NSL_FB + sl) * (DH * BNODES);
    for (int i = tid; i < DH * BNODES; i += 256)
        ps[i] = acc[i >> 4][i & 15];
}

__global__ __launch_bounds__(256) void k_fin1_fb(
    const float* __restrict__ partial, const float* __restrict__ dinv,
    const __hip_bfloat16* __restrict__ hdb, const float* __restrict__ b1,
    const float* __restrict__ W2, const float* __restrict__ b2,
    __hip_bfloat16* __restrict__ qb, float* __restrict__ out, int N) {
    __shared__ float acc[BNODES][DH + 1];
    __shared__ float b1s[DH], W2s[DH];
    const int tid = threadIdx.x;
    if (tid < DH) { b1s[tid] = b1[tid]; W2s[tid] = W2[tid]; }
    const int b = blockIdx.x;
    const float* ps = partial + (size_t)b * NSL_FB * (DH * BNODES);
    for (int i = tid; i < DH * BNODES; i += 256) {
        float s = 0.f;
        #pragma unroll
        for (int sl = 0; sl < NSL_FB; ++sl) s += ps[sl * (DH * BNODES) + i];
        acc[i >> 4][i & 15] = s;
    }
    __syncthreads();
    int node = (b << BSH) + tid;
    if (tid < BNODES && node < N) {
        float dc = dinv[node];
        const __hip_bfloat16* hs = hdb + (size_t)node * DH;
        float t = 0.f;
        #pragma unroll
        for (int f = 0; f < DH; ++f) {
            float hv = __bfloat162float(hs[f]);
            t += fmaxf(dc * (acc[tid][f] + hv) + b1s[f], 0.f) * W2s[f];
        }
        float qq = dc * t;
        qb[node] = __float2bfloat16(qq);
        out[node] = b2[0] + dc * qq;
    }
}

__global__ __launch_bounds__(256) void k_gather2_fb(
    const int* __restrict__ gBase, const uint2* __restrict__ edata,
    const float* __restrict__ dinv, const __hip_bfloat16* __restrict__ qb,
    float* __restrict__ out, int N) {
    __shared__ float a2[BNODES];
    __shared__ uint2 se[SE2_CAP];
    const int tid = threadIdx.x;
    if (tid < BNODES) a2[tid] = 0.f;
    const int b = blockIdx.x;
    const int s = gBase[b], e = gBase[b + 1];
    const int L = e - s;
    const int per = (L + 1) >> 1;
    const int s0 = s + blockIdx.y * per;
    const int e0 = (s0 + per < e) ? (s0 + per) : e;
    const ushort* __restrict__ qp = (const ushort*)qb;
    for (int c0 = s0; c0 < e0; c0 += SE2_CAP) {
        const int len = ((e0 - c0) < SE2_CAP) ? (e0 - c0) : SE2_CAP;
        __syncthreads();
        for (int j = tid; j < len; j += 256) se[j] = ntload_u2(&edata[c0 + j]);
        __syncthreads();
        for (int j = tid; j < len; j += 256) {
            const uint2 ed = se[j];
            const float q = __uint_as_float((uint)qp[ed.x & 0xFFFFFu] << 16);
            atomicAdd(&a2[ed.x >> 20], __uint_as_float(ed.y) * q);
        }
    }
    __syncthreads();
    int node = (b << BSH) + tid;
    if (tid < BNODES && node < N && a2[tid] != 0.f)
        atomicAdd(&out[node], dinv[node] * a2[tid]);
}

// ---------- launcher ----------

extern "C" void kernel_launch(void* const* d_in, const int* in_sizes, int n_in,
                              void* d_out, int out_size, void* d_ws, size_t ws_size,
                              hipStream_t stream) {
    const float* x  = (const float*)d_in[0];
    const int*   ei = (const int*)d_in[1];
    const float* ew = (const float*)d_in[2];
    const float* W1 = (const float*)d_in[3];
    const float* b1 = (const float*)d_in[4];
    const float* W2 = (const float*)d_in[5];
    const float* b2 = (const float*)d_in[6];
    float* out = (float*)d_out;

    const int N = in_sizes[0] / 128;       // 100000
    const int E = in_sizes[2];             // 3200000
    const int* row = ei;
    const int* col = ei + E;
    const int NB = (N + BNODES - 1) >> BSH;   // 1563

    const int hblocks = (E + HCHUNK - 1) / HCHUNK;  // 391
    const int sblocks = (E + CHUNK - 1) / CHUNK;    // 782

    // ---- pregather layout (all fields 16B-multiples; packed) ----
    const int NBp = NB_MAX;                                // 1568
    char* base = (char*)d_ws;
    size_t off = 0;
    int*   gCnt    = (int*)(base + off);   off += (size_t)NBp * 4;
    int*   rCnt    = (int*)(base + off);   off += (size_t)NBp * 4;
    float* deg     = (float*)(base + off); off += (size_t)N * 4;
    int*   gBase   = (int*)(base + off);   off += (size_t)NBp * 4;
    int*   rBase   = (int*)(base + off);   off += (size_t)NBp * 4;
    int*   gCursor = (int*)(base + off);   off += (size_t)NBp * 4;
    int*   rCursor = (int*)(base + off);   off += (size_t)NBp * 4;
    float* dinv    = (float*)(base + off); off += (size_t)N * 4;
    __hip_bfloat16* hdb = (__hip_bfloat16*)(base + off); off += (size_t)16 * N * 2;
    __hip_bfloat16* qe  = (__hip_bfloat16*)(base + off); off += (size_t)E * 2;
    uint*  rrec    = (uint*)(base + off);  off += (size_t)E * 4;
    float* partial = (float*)(base + off); off += (size_t)NB * NSL * (DH * BNODES) * 4;
    uint2* edata   = (uint2*)(base + off); off += (size_t)E * 8;
    int*   pos     = (int*)(base + off);               // overlaid in he region
    uint4* he16    = (uint4*)(base + off);
    const size_t base_need = off;

    int nph = 0;
    int heCap = 0;
    const int cands[4] = {1, 2, 4, 8};
    for (int c = 0; c < 4; ++c) {
        int cap = E / cands[c] + HESLACK;
        if (base_need + (size_t)cap * 32 <= ws_size) { nph = cands[c]; heCap = cap; break; }
    }

    if (nph > 0) {
        // ---- pregather path ----
        hipMemsetAsync(gCnt, 0, ((size_t)2 * NBp + N) * sizeof(int), stream);
        k_hist2<<<hblocks, 256, 0, stream>>>(row, col, gCnt, rCnt, E, NB);
        k_Ascan<<<1, 1024, 0, stream>>>(gCnt, gBase, gCursor, NB, E);
        k_Ascan<<<1, 1024, 0, stream>>>(rCnt, rBase, rCursor, NB, E);
        k_Ascatter<<<sblocks, 256, 0, stream>>>(row, col, ew, gCursor, edata, pos, E, NB);
        k_Rscatter<<<sblocks, 256, 0, stream>>>(row, pos, rCursor, rrec, E, NB);
        k_deg<<<dim3(NB, 2), 256, 0, stream>>>(gBase, edata, deg, N);
        k_h1<<<N / 16, 256, 0, stream>>>(x, W1, deg, dinv, hdb);
        for (int ph = 0; ph < nph; ++ph) {
            int bLo = (int)((long long)NB * ph / nph);
            int bHi = (int)((long long)NB * (ph + 1) / nph);
            k_hgather<<<dim3(NB, 2), 256, 0, stream>>>(rBase, rrec, (const uint*)hdb,
                                                       he16, N, gBase, bLo, bHi, heCap);
            k_gather1_p<<<dim3(bHi - bLo, NSL), 256, 0, stream>>>(gBase, edata, he16,
                                                                  partial, bLo, heCap);
        }
        k_fin1_p<<<NB, 256, 0, stream>>>(partial, dinv, hdb, b1, W2, b2,
                                         rBase, rrec, qe, out, N);
        k_gather2_p<<<dim3(NB, 2), 256, 0, stream>>>(gBase, edata, dinv, qe, out, N);
    } else {
        // ---- fallback: exact R12 layout & schedule (proven ~532us) ----
        const int NBf = (NB + 3) & ~3;
        int* fgCnt    = (int*)d_ws;
        float* fdeg   = (float*)(fgCnt + NBf);
        int* fgBase   = (int*)(fdeg + N);
        int* fgCursor = fgBase + NBf;
        float* fdinv  = (float*)(fgCursor + NBf);
        __hip_bfloat16* fhdb = (__hip_bfloat16*)(fdinv + N);
        __hip_bfloat16* fqb  = fhdb + (size_t)16 * N;
        uintptr_t pp = (uintptr_t)(fqb + N);
        pp = (pp + 15) & ~(uintptr_t)15;
        float* fpartial = (float*)pp;
        uintptr_t ep = (uintptr_t)(fpartial + (size_t)NB * NSL_FB * (DH * BNODES));
        ep = (ep + 15) & ~(uintptr_t)15;
        uint2* fedata = (uint2*)ep;

        hipMemsetAsync(fgCnt, 0, ((size_t)NBf + N) * sizeof(int), stream);
        k_Ahist<<<hblocks, 256, 0, stream>>>(col, fgCnt, E, NB);
        k_Ascan<<<1, 1024, 0, stream>>>(fgCnt, fgBase, fgCursor, NB, E);
        k_Ascatter<<<sblocks, 256, 0, stream>>>(row, col, ew, fgCursor, fedata, nullptr, E, NB);
        k_deg<<<dim3(NB, 2), 256, 0, stream>>>(fgBase, fedata, fdeg, N);
        k_h1<<<N / 16, 256, 0, stream>>>(x, W1, fdeg, fdinv, fhdb);
        k_gather1_fb<<<dim3(NB, NSL_FB), 256, 0, stream>>>(fgBase, fedata, fhdb, fpartial);
        k_fin1_fb<<<NB, 256, 0, stream>>>(fpartial, fdinv, fhdb, b1, W2, b2, fqb, out, N);
        k_gather2_fb<<<dim3(NB, 2), 256, 0, stream>>>(fgBase, fedata, fdinv, fqb, out, N);
    }
}

// Round 9
// 635.167 us; speedup vs baseline: 1.1651x; 1.1000x over previous
//
#include <hip/hip_runtime.h>
#include <hip/hip_bf16.h>

// SectorGCN R16 = R15 resubmit (infra-flake suspected) + alignment hardening.
// Layer 1: R12's scattered-read gather (276us empirical wall; 6 structural
//   variants R7-R14 all >= 276us for moving 32B/edge of h across either the
//   scattered-read path or the scatter-write+readback path).
// Layer 2: dual-sort fix. Ascatter records pos[e] (edge -> col-slot);
//   Rscatter builds row-sorted rrec = pos|rem; fin1q scatters qe[pos]=q[row]
//   (2B fire-and-forget stores, row-bucket-staged); gather2q reads edata+qe
//   DENSE (qe=6.4MB). Replaces R7-R12's ~150us scattered-qb gather2.
// Workspace ~88 MB, 256B-aligned fields (< 115 MB hardware-proven floor from
// R13's successful nph=2 run). N=100000, E=3200000, d_in=128, d_h=16.

#define DH 16
#define BSH 6
#define BNODES 64
#define NB_MAX 1568
#define CHUNK 4096        // scatter chunk
#define HCHUNK 8192       // hist chunk
#define NSLICE 4          // gather1 slices
#define SE_CAP 768        // gather1 staged edges per chunk
#define CH2 1024          // gather2 staged edges per chunk

#define BFL(u) __uint_as_float((u) << 16)
#define BFH(u) __uint_as_float((u) & 0xFFFF0000u)

typedef unsigned int u32x2 __attribute__((ext_vector_type(2)));

static __device__ __forceinline__ uint2 ntload_u2(const uint2* p) {
    u32x2 v = __builtin_nontemporal_load((const u32x2*)p);
    return make_uint2(v.x, v.y);
}

// histogram of BOTH col-buckets and row-buckets in one pass
__global__ __launch_bounds__(256) void k_hist2(const int* __restrict__ row,
                                               const int* __restrict__ col,
                                               int* __restrict__ gCnt,
                                               int* __restrict__ rCnt, int E, int NB) {
    __shared__ int lc[NB_MAX];
    __shared__ int lr[NB_MAX];
    const int tid = threadIdx.x;
    for (int i = tid; i < NB; i += 256) { lc[i] = 0; lr[i] = 0; }
    __syncthreads();
    const int base = blockIdx.x * HCHUNK;
    #pragma unroll
    for (int k = 0; k < 32; ++k) {
        int e = base + tid + 256 * k;
        if (e < E) {
            atomicAdd(&lc[col[e] >> BSH], 1);
            atomicAdd(&lr[row[e] >> BSH], 1);
        }
    }
    __syncthreads();
    for (int i = tid; i < NB; i += 256) {
        if (lc[i]) atomicAdd(&gCnt[i], lc[i]);
        if (lr[i]) atomicAdd(&rCnt[i], lr[i]);
    }
}

// exclusive scan of cnt[NB], NB <= 2048 (2 elems/thread)
__global__ __launch_bounds__(1024) void k_Ascan(const int* __restrict__ cnt,
                                                int* __restrict__ basep,
                                                int* __restrict__ cursor,
                                                int NB, int E) {
    __shared__ int s[1024];
    const int t = threadIdx.x;
    const int i0 = 2 * t, i1 = 2 * t + 1;
    int a = (i0 < NB) ? cnt[i0] : 0;
    int b = (i1 < NB) ? cnt[i1] : 0;
    int v = a + b;
    s[t] = v;
    __syncthreads();
    for (int off = 1; off < 1024; off <<= 1) {
        int u = (t >= off) ? s[t - off] : 0;
        __syncthreads();
        s[t] += u;
        __syncthreads();
    }
    int ex = s[t] - v;
    if (i0 < NB) { basep[i0] = ex;     cursor[i0] = ex; }
    if (i1 < NB) { basep[i1] = ex + a; cursor[i1] = ex + a; }
    if (t == 0) basep[NB] = E;
}

// col-sort scatter; records pos[e] = destination slot of edge e
__global__ __launch_bounds__(256) void k_Ascatter(const int* __restrict__ row,
                                                  const int* __restrict__ col,
                                                  const float* __restrict__ ew,
                                                  int* __restrict__ gCursor,
                                                  uint2* __restrict__ edata,
                                                  int* __restrict__ pos,
                                                  int E, int NB) {
    __shared__ int lh[NB_MAX];      // counts, then (globalRun - localBase)
    __shared__ int lbase[NB_MAX];
    __shared__ int lcur[NB_MAX];
    __shared__ int tsum[256];
    __shared__ unsigned short sbuck[CHUNK];
    __shared__ uint2 stage[CHUNK];  // 32 KB
    const int tid = threadIdx.x;
    for (int i = tid; i < NB; i += 256) lh[i] = 0;
    __syncthreads();
    const int base = blockIdx.x * CHUNK;
    int r_[16], c_[16];
    float w_[16];
    #pragma unroll
    for (int k = 0; k < 16; ++k) {
        int e = base + tid + 256 * k;
        bool ok = e < E;
        c_[k] = ok ? col[e] : -1;
        r_[k] = ok ? row[e] : 0;
        w_[k] = ok ? ew[e] : 0.f;
        if (ok) atomicAdd(&lh[c_[k] >> BSH], 1);
    }
    __syncthreads();
    const int t0 = tid * 8;
    int c8[8];
    int mysum = 0;
    #pragma unroll
    for (int k = 0; k < 8; ++k) {
        c8[k] = (t0 + k < NB) ? lh[t0 + k] : 0;
        mysum += c8[k];
    }
    tsum[tid] = mysum;
    __syncthreads();
    for (int off = 1; off < 256; off <<= 1) {
        int u = (tid >= off) ? tsum[tid - off] : 0;
        __syncthreads();
        tsum[tid] += u;
        __syncthreads();
    }
    int p = tsum[tid] - mysum;
    #pragma unroll
    for (int k = 0; k < 8; ++k) {
        if (t0 + k < NB) { lbase[t0 + k] = p; lcur[t0 + k] = p; }
        p += c8[k];
    }
    __syncthreads();
    for (int b = tid; b < NB; b += 256) {
        int cnt = lh[b];
        if (cnt) {
            int g = atomicAdd(&gCursor[b], cnt);
            lh[b] = g - lbase[b];
        }
    }
    __syncthreads();
    #pragma unroll
    for (int k = 0; k < 16; ++k) {
        if (c_[k] >= 0) {
            int b = c_[k] >> BSH;
            unsigned rem = (unsigned)(c_[k] & (BNODES - 1));
            int sp = atomicAdd(&lcur[b], 1);
            stage[sp] = make_uint2((unsigned)r_[k] | (rem << 20), __float_as_uint(w_[k]));
            sbuck[sp] = (unsigned short)b;
            pos[base + tid + 256 * k] = lh[b] + sp;   // coalesced write
        }
    }
    __syncthreads();
    int nE = E - base;
    if (nE > CHUNK) nE = CHUNK;
    for (int j = tid; j < nE; j += 256)
        edata[lh[sbuck[j]] + j] = stage[j];
}

// row-sort scatter: key = row bucket, payload = pos | row_rem<<26
__global__ __launch_bounds__(256) void k_Rscatter(const int* __restrict__ row,
                                                  const int* __restrict__ pos,
                                                  int* __restrict__ rCursor,
                                                  uint* __restrict__ rrec,
                                                  int E, int NB) {
    __shared__ int lh[NB_MAX];
    __shared__ int lbase[NB_MAX];
    __shared__ int lcur[NB_MAX];
    __shared__ int tsum[256];
    __shared__ unsigned short sbuck[CHUNK];
    __shared__ uint stage[CHUNK];   // 16 KB
    const int tid = threadIdx.x;
    for (int i = tid; i < NB; i += 256) lh[i] = 0;
    __syncthreads();
    const int base = blockIdx.x * CHUNK;
    int r_[16];
    uint p_[16];
    #pragma unroll
    for (int k = 0; k < 16; ++k) {
        int e = base + tid + 256 * k;
        bool ok = e < E;
        r_[k] = ok ? row[e] : -1;
        p_[k] = ok ? (uint)pos[e] : 0u;
        if (ok) atomicAdd(&lh[r_[k] >> BSH], 1);
    }
    __syncthreads();
    const int t0 = tid * 8;
    int c8[8];
    int mysum = 0;
    #pragma unroll
    for (int k = 0; k < 8; ++k) {
        c8[k] = (t0 + k < NB) ? lh[t0 + k] : 0;
        mysum += c8[k];
    }
    tsum[tid] = mysum;
    __syncthreads();
    for (int off = 1; off < 256; off <<= 1) {
        int u = (tid >= off) ? tsum[tid - off] : 0;
        __syncthreads();
        tsum[tid] += u;
        __syncthreads();
    }
    int p = tsum[tid] - mysum;
    #pragma unroll
    for (int k = 0; k < 8; ++k) {
        if (t0 + k < NB) { lbase[t0 + k] = p; lcur[t0 + k] = p; }
        p += c8[k];
    }
    __syncthreads();
    for (int bb = tid; bb < NB; bb += 256) {
        int cnt = lh[bb];
        if (cnt) {
            int g = atomicAdd(&rCursor[bb], cnt);
            lh[bb] = g - lbase[bb];
        }
    }
    __syncthreads();
    #pragma unroll
    for (int k = 0; k < 16; ++k) {
        if (r_[k] >= 0) {
            int bb = r_[k] >> BSH;
            uint rem = (uint)(r_[k] & (BNODES - 1));
            int sp = atomicAdd(&lcur[bb], 1);
            stage[sp] = p_[k] | (rem << 26);
            sbuck[sp] = (unsigned short)bb;
        }
    }
    __syncthreads();
    int nE = E - base;
    if (nE > CHUNK) nE = CHUNK;
    for (int j = tid; j < nE; j += 256)
        rrec[lh[sbuck[j]] + j] = stage[j];
}

// sliced degree: dg[rem] partial in LDS, one global atomic per node per slice
__global__ __launch_bounds__(256) void k_deg(const int* __restrict__ gBase,
                                             const uint2* __restrict__ edata,
                                             float* __restrict__ deg, int N) {
    __shared__ float dg[BNODES];
    const int tid = threadIdx.x;
    if (tid < BNODES) dg[tid] = 0.f;
    __syncthreads();
    const int b = blockIdx.x;
    const int s = gBase[b], e = gBase[b + 1];
    for (int i = s + blockIdx.y * 256 + tid; i < e; i += 512) {
        uint2 ed = ntload_u2(&edata[i]);
        atomicAdd(&dg[ed.x >> 20], __uint_as_float(ed.y));
    }
    __syncthreads();
    int node = (b << BSH) + tid;
    if (tid < BNODES && node < N && dg[tid] != 0.f)
        atomicAdd(&deg[node], dg[tid]);
}

// h~ = rsqrt(deg+1) * (x @ W1) stored as bf16; also stores dinv (fp32).
__global__ __launch_bounds__(256) void k_h1(const float* __restrict__ x,
                                            const float* __restrict__ W1,
                                            const float* __restrict__ deg,
                                            float* __restrict__ dinv,
                                            __hip_bfloat16* __restrict__ hdb) {
    __shared__ float Ws[128 * DH];
    __shared__ float xs[16 * 132];
    const int t = threadIdx.x;
    const int node0 = blockIdx.x * 16;
    #pragma unroll
    for (int i = 0; i < 8; ++i) Ws[t + 256 * i] = W1[t + 256 * i];
    const float4* xg = (const float4*)(x + (size_t)node0 * 128);
    #pragma unroll
    for (int it = 0; it < 2; ++it) {
        int idx = t + 256 * it;
        int n = idx >> 5, k4 = idx & 31;
        float4 v = xg[n * 32 + k4];
        *(float4*)(&xs[n * 132 + k4 * 4]) = v;
    }
    __syncthreads();
    const int node = t >> 4, feat = t & 15;
    const float* xr = &xs[node * 132];
    float acc = 0.f;
    #pragma unroll 8
    for (int k = 0; k < 128; ++k) acc += xr[k] * Ws[k * DH + feat];
    const int v = node0 + node;
    const float di = rsqrtf(deg[v] + 1.0f);
    if (feat == 0) dinv[v] = di;
    hdb[(size_t)v * DH + feat] = __float2bfloat16(di * acc);
}

// layer-1 gather (R12 body, the 276us wall): LDS-staged edata + unroll-8
// tiles; 32 groups x 8 lanes, each lane a bf16x2 feature pair (4B gather).
__global__ __launch_bounds__(256) void k_gather1(
    const int* __restrict__ gBase, const uint2* __restrict__ edata,
    const __hip_bfloat16* __restrict__ hdb, float* __restrict__ partial) {
    __shared__ float acc[BNODES][DH + 1];
    __shared__ uint2 se[SE_CAP];
    const int tid = threadIdx.x;
    for (int i = tid; i < BNODES * (DH + 1); i += 256) ((float*)acc)[i] = 0.f;
    const int b = blockIdx.x, sl = blockIdx.y;
    const int s = gBase[b], e = gBase[b + 1];
    const int L = e - s;
    const int per = (L + NSLICE - 1) / NSLICE;
    const int s0 = s + sl * per;
    const int e0 = (s0 + per < e) ? (s0 + per) : e;
    const int g = tid >> 3;        // 0..31: edge slot within tile
    const int f2 = tid & 7;        // feature pair: feats {2*f2, 2*f2+1}
    const uint* __restrict__ hp = (const uint*)hdb;   // node r: hp[r*8 + f2]

    for (int c0 = s0; c0 < e0; c0 += SE_CAP) {
        const int len = ((e0 - c0) < SE_CAP) ? (e0 - c0) : SE_CAP;
        __syncthreads();           // acc-init done / previous se reads done
        for (int j = tid; j < len; j += 256) se[j] = ntload_u2(&edata[c0 + j]);
        __syncthreads();
        const int nfull = len & ~255;
        for (int j0 = 0; j0 < nfull; j0 += 256) {
            uint2 ed[8];
            uint hv[8];
            #pragma unroll
            for (int k = 0; k < 8; ++k) ed[k] = se[j0 + g + k * 32];
            #pragma unroll
            for (int k = 0; k < 8; ++k)
                hv[k] = hp[(size_t)(ed[k].x & 0xFFFFFu) * 8 + f2];
            #pragma unroll
            for (int k = 0; k < 8; ++k) {
                const float w = __uint_as_float(ed[k].y);
                const int rem = ed[k].x >> 20;
                atomicAdd(&acc[rem][2 * f2],     w * BFL(hv[k]));
                atomicAdd(&acc[rem][2 * f2 + 1], w * BFH(hv[k]));
            }
        }
        for (int j = nfull + g; j < len; j += 32) {
            const uint2 ed = se[j];
            const uint hv = hp[(size_t)(ed.x & 0xFFFFFu) * 8 + f2];
            const float w = __uint_as_float(ed.y);
            const int rem = ed.x >> 20;
            atomicAdd(&acc[rem][2 * f2],     w * BFL(hv));
            atomicAdd(&acc[rem][2 * f2 + 1], w * BFH(hv));
        }
    }
    __syncthreads();
    float* ps = partial + ((size_t)b * NSLICE + sl) * (DH * BNODES);
    for (int i = tid; i < DH * BNODES; i += 256)
        ps[i] = acc[i >> 4][i & 15];
}

// reduce slices + self-loop + bias + relu + dot(W2) -> q; init out;
// then scatter q into edge order: qe[pos] = q[row] (fire-and-forget 2B stores)
__global__ __launch_bounds__(256) void k_fin1q(
    const float* __restrict__ partial, const float* __restrict__ dinv,
    const __hip_bfloat16* __restrict__ hdb, const float* __restrict__ b1,
    const float* __restrict__ W2, const float* __restrict__ b2,
    const int* __restrict__ rBase, const uint* __restrict__ rrec,
    __hip_bfloat16* __restrict__ qe, float* __restrict__ out, int N) {
    __shared__ float acc[BNODES][DH + 1];
    __shared__ float b1s[DH], W2s[DH];
    __shared__ __hip_bfloat16 qls[BNODES];
    const int tid = threadIdx.x;
    if (tid < DH) { b1s[tid] = b1[tid]; W2s[tid] = W2[tid]; }
    const int b = blockIdx.x;
    const float* ps = partial + (size_t)b * NSLICE * (DH * BNODES);
    for (int i = tid; i < DH * BNODES; i += 256) {
        float s = 0.f;
        #pragma unroll
        for (int sl = 0; sl < NSLICE; ++sl) s += ps[sl * (DH * BNODES) + i];
        acc[i >> 4][i & 15] = s;
    }
    __syncthreads();
    int node = (b << BSH) + tid;
    if (tid < BNODES && node < N) {
        float dc = dinv[node];
        const __hip_bfloat16* hs = hdb + (size_t)node * DH;
        float t = 0.f;
        #pragma unroll
        for (int f = 0; f < DH; ++f) {
            float hv = __bfloat162float(hs[f]);
            t += fmaxf(dc * (acc[tid][f] + hv) + b1s[f], 0.f) * W2s[f];
        }
        float qq = dc * t;
        qls[tid] = __float2bfloat16(qq);
        out[node] = b2[0] + dc * qq;    // bias + self-loop term of layer 2
    } else if (tid < BNODES) {
        qls[tid] = __float2bfloat16(0.f);
    }
    __syncthreads();
    const int r0 = rBase[b], r1 = rBase[b + 1];
    for (int j = r0 + tid; j < r1; j += 256) {
        uint rec = rrec[j];
        qe[rec & 0x03FFFFFFu] = qls[rec >> 26];
    }
}

// layer-2: DENSE staged reads (edata + qe chunks in LDS), a2[rem] LDS atomic;
// out[node] += dinv*a2 (1 global atomic per node per half)
__global__ __launch_bounds__(256) void k_gather2q(
    const int* __restrict__ gBase, const uint2* __restrict__ edata,
    const float* __restrict__ dinv, const __hip_bfloat16* __restrict__ qe,
    float* __restrict__ out, int N) {
    __shared__ float a2[BNODES];
    __shared__ uint2 se[CH2];      // 8 KB
    __shared__ ushort sq[CH2];     // 2 KB
    const int tid = threadIdx.x;
    if (tid < BNODES) a2[tid] = 0.f;
    const int b = blockIdx.x;
    const int s = gBase[b], e = gBase[b + 1];
    const int L = e - s;
    const int per = (L + 1) >> 1;
    const int s0 = s + blockIdx.y * per;
    const int e0 = (s0 + per < e) ? (s0 + per) : e;
    const ushort* __restrict__ qp = (const ushort*)qe;

    for (int c0 = s0; c0 < e0; c0 += CH2) {
        const int len = ((e0 - c0) < CH2) ? (e0 - c0) : CH2;
        __syncthreads();
        for (int i = tid; i < len; i += 256) se[i] = ntload_u2(&edata[c0 + i]);
        for (int i = tid; i < len; i += 256) sq[i] = qp[c0 + i];
        __syncthreads();
        #pragma unroll
        for (int k = 0; k < CH2 / 256; ++k) {
            const int idx = tid + k * 256;
            if (idx < len) {
                const uint2 d = se[idx];
                const float q = __uint_as_float((uint)sq[idx] << 16);
                atomicAdd(&a2[d.x >> 20], __uint_as_float(d.y) * q);
            }
        }
    }
    __syncthreads();
    int node = (b << BSH) + tid;
    if (tid < BNODES && node < N && a2[tid] != 0.f)
        atomicAdd(&out[node], dinv[node] * a2[tid]);
}

extern "C" void kernel_launch(void* const* d_in, const int* in_sizes, int n_in,
                              void* d_out, int out_size, void* d_ws, size_t ws_size,
                              hipStream_t stream) {
    const float* x  = (const float*)d_in[0];
    const int*   ei = (const int*)d_in[1];
    const float* ew = (const float*)d_in[2];
    const float* W1 = (const float*)d_in[3];
    const float* b1 = (const float*)d_in[4];
    const float* W2 = (const float*)d_in[5];
    const float* b2 = (const float*)d_in[6];
    float* out = (float*)d_out;

    const int N = in_sizes[0] / 128;       // 100000
    const int E = in_sizes[2];             // 3200000
    const int* row = ei;
    const int* col = ei + E;
    const int NB = (N + BNODES - 1) >> BSH;   // 1563
    const int NBp = NB_MAX;                   // 1568 (>= NB+1)

    const int hblocks = (E + HCHUNK - 1) / HCHUNK;  // 391
    const int sblocks = (E + CHUNK - 1) / CHUNK;    // 782

    // ---- layout (~88 MB, 256B-aligned fields; < 115 MB HW-proven floor) ----
    char* base = (char*)d_ws;
    size_t off = 0;
    #define ALLOC(ptr_t, name, bytes) \
        ptr_t name = (ptr_t)(base + off); off = (off + (size_t)(bytes) + 255) & ~(size_t)255;
    ALLOC(int*,   gCnt,    (size_t)NBp * 4)
    ALLOC(int*,   rCnt,    (size_t)NBp * 4)
    ALLOC(float*, deg,     (size_t)N * 4)
    ALLOC(int*,   gBase,   (size_t)NBp * 4)
    ALLOC(int*,   rBase,   (size_t)NBp * 4)
    ALLOC(int*,   gCursor, (size_t)NBp * 4)
    ALLOC(int*,   rCursor, (size_t)NBp * 4)
    ALLOC(float*, dinv,    (size_t)N * 4)
    ALLOC(__hip_bfloat16*, hdb, (size_t)16 * N * 2)                 // 3.2 MB
    ALLOC(__hip_bfloat16*, qe,  (size_t)E * 2)                      // 6.4 MB
    ALLOC(int*,   pos,     (size_t)E * 4)                           // 12.8 MB
    ALLOC(uint*,  rrec,    (size_t)E * 4)                           // 12.8 MB
    ALLOC(float*, partial, (size_t)NB * NSLICE * (DH * BNODES) * 4) // 25.6 MB
    ALLOC(uint2*, edata,   (size_t)E * 8)                           // 25.6 MB
    #undef ALLOC

    hipMemsetAsync(gCnt, 0, ((size_t)NBp) * sizeof(int), stream);
    hipMemsetAsync(rCnt, 0, ((size_t)NBp) * sizeof(int), stream);
    hipMemsetAsync(deg,  0, ((size_t)N) * sizeof(float), stream);
    k_hist2<<<hblocks, 256, 0, stream>>>(row, col, gCnt, rCnt, E, NB);
    k_Ascan<<<1, 1024, 0, stream>>>(gCnt, gBase, gCursor, NB, E);
    k_Ascan<<<1, 1024, 0, stream>>>(rCnt, rBase, rCursor, NB, E);
    k_Ascatter<<<sblocks, 256, 0, stream>>>(row, col, ew, gCursor, edata, pos, E, NB);
    k_Rscatter<<<sblocks, 256, 0, stream>>>(row, pos, rCursor, rrec, E, NB);
    k_deg<<<dim3(NB, 2), 256, 0, stream>>>(gBase, edata, deg, N);
    k_h1<<<N / 16, 256, 0, stream>>>(x, W1, deg, dinv, hdb);
    k_gather1<<<dim3(NB, NSLICE), 256, 0, stream>>>(gBase, edata, hdb, partial);
    k_fin1q<<<NB, 256, 0, stream>>>(partial, dinv, hdb, b1, W2, b2,
                                    rBase, rrec, qe, out, N);
    k_gather2q<<<dim3(NB, 2), 256, 0, stream>>>(gBase, edata, dinv, qe, out, N);
}